// Round 2
// baseline (531.722 us; speedup 1.0000x reference)
//
#include <hip/hip_runtime.h>
#include <math.h>

#define T_TOKENS 32768
#define HIDDEN   2048
#define NE       8
#define NT       4          // tokens per wave per group (must be 4: 32 values = NT*NE)
#define BLOCK    512
#define GRID     512
#define NWAVES   (GRID * (BLOCK / 64))

// ws layout (floats): [0..7]=importance sums, [8..15]=load counts, [16]=sum(lse^2)
__global__ __launch_bounds__(BLOCK, 4) void router_main(
    const float* __restrict__ x, const float* __restrict__ W,
    float* __restrict__ out, float* __restrict__ ws)
{
    __shared__ float w_lds[NE * HIDDEN];   // 64 KiB
    __shared__ float s_acc[17];

    if (threadIdx.x < 17) s_acc[threadIdx.x] = 0.0f;

    // Stage W into LDS: 16384 floats, 512 threads * float4 = 2048 floats/iter
#pragma unroll
    for (int j = 0; j < (NE * HIDDEN) / (BLOCK * 4); ++j) {
        const int idx = 4 * (threadIdx.x + BLOCK * j);
        *(float4*)&w_lds[idx] = *(const float4*)&W[idx];
    }
    __syncthreads();

    const int lane = threadIdx.x & 63;
    const int wave = blockIdx.x * (BLOCK / 64) + (threadIdx.x >> 6);

    for (int g = wave; g < T_TOKENS / NT; g += NWAVES) {
        const int t0 = g * NT;
        const float* xp = x + (size_t)t0 * HIDDEN + lane * 4;

        // v[t*8+e] = partial dot of token t with expert e (this lane's slice)
        float v[NT * NE];
#pragma unroll
        for (int i = 0; i < NT * NE; ++i) v[i] = 0.0f;

        // 2-deep prefetch pipeline over 8 chunks of 256 floats
        float4 xbuf[3][NT];
#pragma unroll
        for (int t = 0; t < NT; ++t)
            xbuf[0][t] = *(const float4*)(xp + (size_t)t * HIDDEN);
#pragma unroll
        for (int t = 0; t < NT; ++t)
            xbuf[1][t] = *(const float4*)(xp + (size_t)t * HIDDEN + 256);

#pragma unroll
        for (int c = 0; c < HIDDEN / 256; ++c) {
            if (c + 2 < HIDDEN / 256) {
#pragma unroll
                for (int t = 0; t < NT; ++t)
                    xbuf[(c + 2) % 3][t] =
                        *(const float4*)(xp + (size_t)t * HIDDEN + (c + 2) * 256);
            }
#pragma unroll
            for (int e = 0; e < NE; ++e) {
                const float4 wv = *(const float4*)&w_lds[e * HIDDEN + c * 256 + lane * 4];
#pragma unroll
                for (int t = 0; t < NT; ++t) {
                    const float4 xv = xbuf[c % 3][t];
                    v[t * 8 + e] = fmaf(xv.x, wv.x,
                                   fmaf(xv.y, wv.y,
                                   fmaf(xv.z, wv.z,
                                   fmaf(xv.w, wv.w, v[t * 8 + e]))));
                }
            }
        }

        // ---- value-pairing butterfly: 32 values x 64 lanes -> lane l holds
        // the fully-summed value (l & 31), i.e. token (l>>3)&3, expert l&7.
#pragma unroll
        for (int step = 0; step < 5; ++step) {
            const int m = 1 << step;
            const int n = 32 >> step;
            const bool hi = (lane & m) != 0;
#pragma unroll
            for (int i = 0; i < n / 2; ++i) {
                const float a = v[2 * i], b = v[2 * i + 1];
                const float keep = hi ? b : a;
                const float send = hi ? a : b;
                v[i] = keep + __shfl_xor(send, m, 64);
            }
        }
        v[0] += __shfl_xor(v[0], 32, 64);   // combine the two 32-lane halves

        // ---- wave-parallel epilogue: 8-lane group per token
        const int e = lane & 7;
        const int tk = t0 + ((lane >> 3) & 3);
        const float lg = v[0];

        float mx = lg;
#pragma unroll
        for (int m2 = 1; m2 <= 4; m2 <<= 1) mx = fmaxf(mx, __shfl_xor(mx, m2, 64));
        const float p = __expf(lg - mx);
        float sm = p;
#pragma unroll
        for (int m2 = 1; m2 <= 4; m2 <<= 1) sm += __shfl_xor(sm, m2, 64);
        const float inv = 1.0f / sm;
        const float lse = mx + __logf(sm);
        const float prob = p * inv;

        // top-1 (lower index wins ties)
        float bv = prob; int be = e;
#pragma unroll
        for (int m2 = 1; m2 <= 4; m2 <<= 1) {
            const float ov = __shfl_xor(bv, m2, 64);
            const int   oe = __shfl_xor(be, m2, 64);
            if (ov > bv || (ov == bv && oe < be)) { bv = ov; be = oe; }
        }
        // top-2: exclude be
        float cv = (e == be) ? -1.0f : prob; int ce = e;
#pragma unroll
        for (int m2 = 1; m2 <= 4; m2 <<= 1) {
            const float ov = __shfl_xor(cv, m2, 64);
            const int   oe = __shfl_xor(ce, m2, 64);
            if (ov > cv || (ov == cv && oe < ce)) { cv = ov; ce = oe; }
        }

        if (lane < 32) {
            atomicAdd(&s_acc[e], prob);                 // importance
            if (e == 0) {
                const float denom = fmaxf(bv + cv, 1e-9f);
                float2 ex = make_float2((float)be, (float)ce);
                float2 sc = make_float2(bv / denom, cv / denom);
                *(float2*)&out[2 * tk] = ex;
                *(float2*)&out[2 * T_TOKENS + 2 * tk] = sc;
                atomicAdd(&s_acc[8 + be], 1.0f);        // load (top-1 count)
                atomicAdd(&s_acc[16], lse * lse);       // z accumulator
            }
        }
    }

    __syncthreads();
    if (threadIdx.x < 17) atomicAdd(&ws[threadIdx.x], s_acc[threadIdx.x]);
}

__global__ void router_finalize(const float* __restrict__ ws, float* __restrict__ out)
{
    float impsum = 0.0f, loadsum = 0.0f;
#pragma unroll
    for (int e = 0; e < NE; ++e) { impsum += ws[e]; loadsum += ws[8 + e]; }
    impsum  = fmaxf(impsum, 1e-9f);
    loadsum = fmaxf(loadsum, 1e-9f);
    float lb = 0.0f;
#pragma unroll
    for (int e = 0; e < NE; ++e)
        lb += (ws[e] / impsum) * (ws[8 + e] / loadsum);
    lb *= (float)(NE * NE) * 0.01f;                    // * NUM_EXPERTS^2 * LB_LOSS_COEF
    const float z = ws[16] / (float)T_TOKENS * 0.001f; // mean(lse^2) * Z_LOSS_COEF

    out[4 * T_TOKENS + 0] = z;   // index 131072
    out[4 * T_TOKENS + 1] = lb;  // index 131073
}

extern "C" void kernel_launch(void* const* d_in, const int* in_sizes, int n_in,
                              void* d_out, int out_size, void* d_ws, size_t ws_size,
                              hipStream_t stream)
{
    const float* x = (const float*)d_in[0];
    const float* W = (const float*)d_in[1];
    float* out = (float*)d_out;
    float* ws  = (float*)d_ws;

    hipMemsetAsync(ws, 0, 17 * sizeof(float), stream);
    router_main<<<GRID, BLOCK, 0, stream>>>(x, W, out, ws);
    router_finalize<<<1, 1, 0, stream>>>(ws, out);
}

// Round 5
// 373.997 us; speedup vs baseline: 1.4217x; 1.4217x over previous
//
#include <hip/hip_runtime.h>
#include <math.h>

#define T_TOKENS 32768
#define HIDDEN   2048
#define NE       8
#define NT       2            // tokens per wave per group
#define BLOCK    512
#define GRID     512
#define NWAVES   (GRID * (BLOCK / 64))          // 4096
#define NGROUPS  (T_TOKENS / NT)                // 16384
#define GPW      (NGROUPS / NWAVES)             // 4 groups per wave
#define NCHUNK   (HIDDEN / 256)                 // 8 chunks of 256 floats

// ws layout (floats): [0..7]=importance sums, [8..15]=load counts, [16]=sum(lse^2)
__global__ __launch_bounds__(BLOCK, 2) void router_main(
    const float* __restrict__ x, const float* __restrict__ W,
    float* __restrict__ out, float* __restrict__ ws)
{
    __shared__ float w_lds[NE * HIDDEN];   // 64 KiB
    __shared__ float s_acc[17];

    if (threadIdx.x < 17) s_acc[threadIdx.x] = 0.0f;

    // Stage W into LDS: 16384 floats, 512 threads * float4 = 2048 floats/iter
#pragma unroll
    for (int j = 0; j < (NE * HIDDEN) / (BLOCK * 4); ++j) {
        const int idx = 4 * (threadIdx.x + BLOCK * j);
        *(float4*)&w_lds[idx] = *(const float4*)&W[idx];
    }
    __syncthreads();

    const int lane = threadIdx.x & 63;
    const int wave = blockIdx.x * (BLOCK / 64) + (threadIdx.x >> 6);

    // Base pointer for this wave's first group; groups stride by NWAVES.
    const float* xp = x + (size_t)(wave * NT) * HIDDEN + lane * 4;
    const size_t gstride = (size_t)NWAVES * NT * HIDDEN;   // floats between groups

    // Full 2-token row set in registers: xb[t][c], 16 float4 = 64 VGPRs.
    float4 xb[NT][NCHUNK];

    // Prologue: issue all 16 loads for group 0.
#pragma unroll
    for (int c = 0; c < NCHUNK; ++c)
#pragma unroll
        for (int t = 0; t < NT; ++t)
            xb[t][c] = *(const float4*)(xp + (size_t)t * HIDDEN + c * 256);

#pragma unroll
    for (int i = 0; i < GPW; ++i) {
        const int g  = wave + i * NWAVES;
        const int t0 = g * NT;
        const float* xnext = xp + (size_t)(i + 1) * gstride;

        float v[NT * NE];
#pragma unroll
        for (int k = 0; k < NT * NE; ++k) v[k] = 0.0f;

#pragma unroll
        for (int c = 0; c < NCHUNK; ++c) {
            // consume chunk c
#pragma unroll
            for (int e = 0; e < NE; ++e) {
                const float4 wv = *(const float4*)&w_lds[e * HIDDEN + c * 256 + lane * 4];
#pragma unroll
                for (int t = 0; t < NT; ++t) {
                    const float4 xv = xb[t][c];
                    v[t * NE + e] = fmaf(xv.x, wv.x,
                                    fmaf(xv.y, wv.y,
                                    fmaf(xv.z, wv.z,
                                    fmaf(xv.w, wv.w, v[t * NE + e]))));
                }
            }
            // immediately refill chunk c with next group's data — these 16
            // loads stay in flight through the reduce + epilogue below.
            if (i + 1 < GPW) {
#pragma unroll
                for (int t = 0; t < NT; ++t)
                    xb[t][c] = *(const float4*)(xnext + (size_t)t * HIDDEN + c * 256);
            }
        }

        // ---- value-pairing butterfly: 16 values x 64 lanes.
        // After 4 steps lane l holds value (l&15) summed over its 16-lane
        // group: token (l>>3)&1, expert l&7. Two more adds finish 64 lanes.
#pragma unroll
        for (int step = 0; step < 4; ++step) {
            const int m = 1 << step;
            const int n = 16 >> step;
            const bool hi = (lane & m) != 0;
#pragma unroll
            for (int k = 0; k < n / 2; ++k) {
                const float a = v[2 * k], b = v[2 * k + 1];
                const float keep = hi ? b : a;
                const float send = hi ? a : b;
                v[k] = keep + __shfl_xor(send, m, 64);
            }
        }
        v[0] += __shfl_xor(v[0], 16, 64);
        v[0] += __shfl_xor(v[0], 32, 64);

        // ---- wave-parallel epilogue: 8-lane group per token (4x replicated)
        const int e  = lane & 7;
        const int tk = t0 + ((lane >> 3) & 1);
        const float lg = v[0];

        float mx = lg;
#pragma unroll
        for (int m2 = 1; m2 <= 4; m2 <<= 1) mx = fmaxf(mx, __shfl_xor(mx, m2, 64));
        const float p = __expf(lg - mx);
        float sm = p;
#pragma unroll
        for (int m2 = 1; m2 <= 4; m2 <<= 1) sm += __shfl_xor(sm, m2, 64);
        const float inv = 1.0f / sm;
        const float lse = mx + __logf(sm);
        const float prob = p * inv;

        // top-1 (lower index wins ties)
        float bv = prob; int be = e;
#pragma unroll
        for (int m2 = 1; m2 <= 4; m2 <<= 1) {
            const float ov = __shfl_xor(bv, m2, 64);
            const int   oe = __shfl_xor(be, m2, 64);
            if (ov > bv || (ov == bv && oe < be)) { bv = ov; be = oe; }
        }
        // top-2: exclude be
        float cv = (e == be) ? -1.0f : prob; int ce = e;
#pragma unroll
        for (int m2 = 1; m2 <= 4; m2 <<= 1) {
            const float ov = __shfl_xor(cv, m2, 64);
            const int   oe = __shfl_xor(ce, m2, 64);
            if (ov > cv || (ov == cv && oe < ce)) { cv = ov; ce = oe; }
        }

        if (lane < 16) {
            atomicAdd(&s_acc[e], prob);                 // importance (one replica)
            if (e == 0) {                               // lanes 0 (t0) and 8 (t0+1)
                const float denom = fmaxf(bv + cv, 1e-9f);
                float2 ex = make_float2((float)be, (float)ce);
                float2 sc = make_float2(bv / denom, cv / denom);
                *(float2*)&out[2 * tk] = ex;
                *(float2*)&out[2 * T_TOKENS + 2 * tk] = sc;
                atomicAdd(&s_acc[8 + be], 1.0f);        // load (top-1 count)
                atomicAdd(&s_acc[16], lse * lse);       // z accumulator
            }
        }
    }

    __syncthreads();
    if (threadIdx.x < 17) atomicAdd(&ws[threadIdx.x], s_acc[threadIdx.x]);
}

__global__ void router_finalize(const float* __restrict__ ws, float* __restrict__ out)
{
    float impsum = 0.0f, loadsum = 0.0f;
#pragma unroll
    for (int e = 0; e < NE; ++e) { impsum += ws[e]; loadsum += ws[8 + e]; }
    impsum  = fmaxf(impsum, 1e-9f);
    loadsum = fmaxf(loadsum, 1e-9f);
    float lb = 0.0f;
#pragma unroll
    for (int e = 0; e < NE; ++e)
        lb += (ws[e] / impsum) * (ws[8 + e] / loadsum);
    lb *= (float)(NE * NE) * 0.01f;                    // * NUM_EXPERTS^2 * LB_LOSS_COEF
    const float z = ws[16] / (float)T_TOKENS * 0.001f; // mean(lse^2) * Z_LOSS_COEF

    out[4 * T_TOKENS + 0] = z;   // index 131072
    out[4 * T_TOKENS + 1] = lb;  // index 131073
}

extern "C" void kernel_launch(void* const* d_in, const int* in_sizes, int n_in,
                              void* d_out, int out_size, void* d_ws, size_t ws_size,
                              hipStream_t stream)
{
    const float* x = (const float*)d_in[0];
    const float* W = (const float*)d_in[1];
    float* out = (float*)d_out;
    float* ws  = (float*)d_ws;

    hipMemsetAsync(ws, 0, 17 * sizeof(float), stream);
    router_main<<<GRID, BLOCK, 0, stream>>>(x, W, out, ws);
    router_finalize<<<1, 1, 0, stream>>>(ws, out);
}

// Round 6
// 360.436 us; speedup vs baseline: 1.4752x; 1.0376x over previous
//
#include <hip/hip_runtime.h>
#include <math.h>

#define T_TOKENS 32768
#define HIDDEN   2048
#define NE       8
#define NT       2
#define BLOCK    1024
#define WPB      (BLOCK / 64)                 // 16 waves per block
#define GRID     256
#define NWAVES   (GRID * WPB)                 // 4096
#define NGROUPS  (T_TOKENS / NT)              // 16384
#define GPW      (NGROUPS / NWAVES)           // 4 groups per wave
#define NCHUNK   (HIDDEN / 256)               // 8 chunks of 256 floats
#define NSTEP    (GPW * NCHUNK)               // 32 chunk-steps per wave

// ws layout (floats): [0..7]=importance sums, [8..15]=load counts, [16]=sum(lse^2)
__global__ __launch_bounds__(BLOCK, 1) void router_main(
    const float* __restrict__ x, const float* __restrict__ W,
    float* __restrict__ out, float* __restrict__ ws)
{
    __shared__ float w_lds[NE * HIDDEN];            // 64 KiB
    __shared__ float xstage[WPB][2][NT * 256];      // 64 KiB: per-wave dbuf, 2 tokens x 1 KiB
    __shared__ float s_acc[17];

    if (threadIdx.x < 17) s_acc[threadIdx.x] = 0.0f;

    // Stage W into LDS: 16384 floats, 1024 threads * float4 = 4096 floats/iter
#pragma unroll
    for (int j = 0; j < (NE * HIDDEN) / (BLOCK * 4); ++j) {
        const int idx = 4 * (threadIdx.x + BLOCK * j);
        *(float4*)&w_lds[idx] = *(const float4*)&W[idx];
    }
    __syncthreads();

    const int lane = threadIdx.x & 63;
    const int wid  = threadIdx.x >> 6;
    const int wave = blockIdx.x * WPB + wid;

    // per-lane global base; chunk-step s covers group s>>3, chunk s&7
    const float* xp = x + (size_t)(wave * NT) * HIDDEN + lane * 4;
    const size_t gstride = (size_t)NWAVES * NT * HIDDEN;

    float* stg0 = &xstage[wid][0][0];
    float* stg1 = &xstage[wid][1][0];

    // Async-stage step s into buffer s&1: 2 x global_load_lds (64 lanes x 16 B
    // each = 1 KiB/token). Global src is per-lane; LDS dest is wave-uniform
    // base + lane*16, matching lane*4-float read layout (linear, no swizzle).
    auto issue = [&](int s) {
        const float* g = xp + (size_t)(s >> 3) * gstride + (size_t)(s & 7) * 256;
        float* dst = (s & 1) ? stg1 : stg0;
        __builtin_amdgcn_global_load_lds(
            (const __attribute__((address_space(1))) void*)g,
            (__attribute__((address_space(3))) void*)dst, 16, 0, 0);
        __builtin_amdgcn_global_load_lds(
            (const __attribute__((address_space(1))) void*)(g + HIDDEN),
            (__attribute__((address_space(3))) void*)(dst + 256), 16, 0, 0);
    };

    issue(0);
    issue(1);

#pragma unroll
    for (int i = 0; i < GPW; ++i) {
        const int t0 = (wave + i * NWAVES) * NT;

        float v[NT * NE];
#pragma unroll
        for (int k = 0; k < NT * NE; ++k) v[k] = 0.0f;

#pragma unroll
        for (int c = 0; c < NCHUNK; ++c) {
            const int s = i * NCHUNK + c;

            // W fragments first: these ds_reads overlap the vmcnt wait below.
            float4 wv[NE];
#pragma unroll
            for (int e = 0; e < NE; ++e)
                wv[e] = *(const float4*)&w_lds[e * HIDDEN + c * 256 + lane * 4];

            // Counted wait: 2 younger loads (step s+1) may stay in flight.
            // Epilogue stores are younger still, so vmcnt(2) remains correct
            // (FIFO retirement). Last step has nothing younger -> vmcnt(0).
            if (s == NSTEP - 1) asm volatile("s_waitcnt vmcnt(0)" ::: "memory");
            else                asm volatile("s_waitcnt vmcnt(2)" ::: "memory");

            const float* xs = (s & 1) ? stg1 : stg0;
            const float4 xv0 = *(const float4*)&xs[lane * 4];
            const float4 xv1 = *(const float4*)&xs[256 + lane * 4];

#pragma unroll
            for (int e = 0; e < NE; ++e) {
                v[e]      = fmaf(xv0.x, wv[e].x, fmaf(xv0.y, wv[e].y,
                            fmaf(xv0.z, wv[e].z, fmaf(xv0.w, wv[e].w, v[e]))));
                v[NE + e] = fmaf(xv1.x, wv[e].x, fmaf(xv1.y, wv[e].y,
                            fmaf(xv1.z, wv[e].z, fmaf(xv1.w, wv[e].w, v[NE + e]))));
            }

            if (s + 2 < NSTEP) {
                // ds_reads of this buffer must retire before the DMA overwrite.
                asm volatile("s_waitcnt lgkmcnt(0)" ::: "memory");
                issue(s + 2);
            }
        }

        // ---- value-pairing butterfly: 16 values x 64 lanes.
        // After 4 steps lane l holds value (l&15) summed over its 16-lane
        // group: token (l>>3)&1, expert l&7. Two more adds finish 64 lanes.
#pragma unroll
        for (int step = 0; step < 4; ++step) {
            const int m = 1 << step;
            const int n = 16 >> step;
            const bool hi = (lane & m) != 0;
#pragma unroll
            for (int k = 0; k < n / 2; ++k) {
                const float a = v[2 * k], b = v[2 * k + 1];
                const float keep = hi ? b : a;
                const float send = hi ? a : b;
                v[k] = keep + __shfl_xor(send, m, 64);
            }
        }
        v[0] += __shfl_xor(v[0], 16, 64);
        v[0] += __shfl_xor(v[0], 32, 64);

        // ---- wave-parallel epilogue: 8-lane group per token (4x replicated)
        const int e  = lane & 7;
        const int tk = t0 + ((lane >> 3) & 1);
        const float lg = v[0];

        float mx = lg;
#pragma unroll
        for (int m2 = 1; m2 <= 4; m2 <<= 1) mx = fmaxf(mx, __shfl_xor(mx, m2, 64));
        const float p = __expf(lg - mx);
        float sm = p;
#pragma unroll
        for (int m2 = 1; m2 <= 4; m2 <<= 1) sm += __shfl_xor(sm, m2, 64);
        const float inv = 1.0f / sm;
        const float lse = mx + __logf(sm);
        const float prob = p * inv;

        // top-1 (lower index wins ties)
        float bv = prob; int be = e;
#pragma unroll
        for (int m2 = 1; m2 <= 4; m2 <<= 1) {
            const float ov = __shfl_xor(bv, m2, 64);
            const int   oe = __shfl_xor(be, m2, 64);
            if (ov > bv || (ov == bv && oe < be)) { bv = ov; be = oe; }
        }
        // top-2: exclude be
        float cv = (e == be) ? -1.0f : prob; int ce = e;
#pragma unroll
        for (int m2 = 1; m2 <= 4; m2 <<= 1) {
            const float ov = __shfl_xor(cv, m2, 64);
            const int   oe = __shfl_xor(ce, m2, 64);
            if (ov > cv || (ov == cv && oe < ce)) { cv = ov; ce = oe; }
        }

        if (lane < 16) {
            atomicAdd(&s_acc[e], prob);                 // importance (one replica)
            if (e == 0) {                               // lanes 0 (t0) and 8 (t0+1)
                const float denom = fmaxf(bv + cv, 1e-9f);
                float2 ex = make_float2((float)be, (float)ce);
                float2 sc = make_float2(bv / denom, cv / denom);
                *(float2*)&out[2 * tk] = ex;
                *(float2*)&out[2 * T_TOKENS + 2 * tk] = sc;
                atomicAdd(&s_acc[8 + be], 1.0f);        // load (top-1 count)
                atomicAdd(&s_acc[16], lse * lse);       // z accumulator
            }
        }
    }

    __syncthreads();
    if (threadIdx.x < 17) atomicAdd(&ws[threadIdx.x], s_acc[threadIdx.x]);
}

__global__ void router_finalize(const float* __restrict__ ws, float* __restrict__ out)
{
    float impsum = 0.0f, loadsum = 0.0f;
#pragma unroll
    for (int e = 0; e < NE; ++e) { impsum += ws[e]; loadsum += ws[8 + e]; }
    impsum  = fmaxf(impsum, 1e-9f);
    loadsum = fmaxf(loadsum, 1e-9f);
    float lb = 0.0f;
#pragma unroll
    for (int e = 0; e < NE; ++e)
        lb += (ws[e] / impsum) * (ws[8 + e] / loadsum);
    lb *= (float)(NE * NE) * 0.01f;                    // * NUM_EXPERTS^2 * LB_LOSS_COEF
    const float z = ws[16] / (float)T_TOKENS * 0.001f; // mean(lse^2) * Z_LOSS_COEF

    out[4 * T_TOKENS + 0] = z;   // index 131072
    out[4 * T_TOKENS + 1] = lb;  // index 131073
}

extern "C" void kernel_launch(void* const* d_in, const int* in_sizes, int n_in,
                              void* d_out, int out_size, void* d_ws, size_t ws_size,
                              hipStream_t stream)
{
    const float* x = (const float*)d_in[0];
    const float* W = (const float*)d_in[1];
    float* out = (float*)d_out;
    float* ws  = (float*)d_ws;

    hipMemsetAsync(ws, 0, 17 * sizeof(float), stream);
    router_main<<<GRID, BLOCK, 0, stream>>>(x, W, out, ws);
    router_finalize<<<1, 1, 0, stream>>>(ws, out);
}